// Round 1
// baseline (11591.008 us; speedup 1.0000x reference)
//
#include <hip/hip_runtime.h>
#include <math.h>

#define SLEN 4096
#define EDIM 256
#define HDIM 256
#define G4   1024
#define NTAG 5
#define NEGV -10000.0f
#define START_TAG 3
#define STOP_TAG 4

// ---------------------------------------------------------------------------
// Kernel A: xg[d][t][r] = b_d[r] + sum_k embed[sentence[t]][k] * w_ih_d[r][k]
// Tiled f32 GEMM with fused embedding gather. Tiles 64(M=t) x 64(N=row), BK=32.
// ---------------------------------------------------------------------------
__global__ __launch_bounds__(256) void xg_gemm(
    const float* __restrict__ embed, const int* __restrict__ sent,
    const float* __restrict__ wih_f, const float* __restrict__ b_f,
    const float* __restrict__ wih_b, const float* __restrict__ b_b,
    float* __restrict__ xg_f, float* __restrict__ xg_b) {
  const int dir = blockIdx.z;
  const float* wih  = dir ? wih_b : wih_f;
  const float* bias = dir ? b_b  : b_f;
  float* out        = dir ? xg_b : xg_f;
  const int m0 = blockIdx.x * 64;   // t tile
  const int n0 = blockIdx.y * 64;   // gate-row tile

  __shared__ float As[32][64];      // [k][m]
  __shared__ float Bs[32][64];      // [k][n]
  __shared__ int   srow[64];

  const int tid = threadIdx.x;
  if (tid < 64) srow[tid] = sent[m0 + tid];
  __syncthreads();

  const int tn0 = (tid & 15) * 4;
  const int tm0 = (tid >> 4) * 4;
  float acc[4][4];
#pragma unroll
  for (int i = 0; i < 4; i++)
#pragma unroll
    for (int j = 0; j < 4; j++) acc[i][j] = 0.f;

  const int msl = tid & 63;          // staging row within tile
  const int k4b = tid >> 6;          // 0..3

  for (int kk = 0; kk < EDIM; kk += 32) {
    __syncthreads();
    // stage A (gathered embed) and B (w_ih), transposed into [k][m] layout
    {
      const int row = srow[msl];
#pragma unroll
      for (int rep = 0; rep < 2; rep++) {
        const int k4 = k4b + rep * 4;  // 0..7
        const float4 v = *(const float4*)(embed + (size_t)row * EDIM + kk + k4 * 4);
        As[k4 * 4 + 0][msl] = v.x; As[k4 * 4 + 1][msl] = v.y;
        As[k4 * 4 + 2][msl] = v.z; As[k4 * 4 + 3][msl] = v.w;
      }
#pragma unroll
      for (int rep = 0; rep < 2; rep++) {
        const int k4 = k4b + rep * 4;
        const float4 v = *(const float4*)(wih + (size_t)(n0 + msl) * EDIM + kk + k4 * 4);
        Bs[k4 * 4 + 0][msl] = v.x; Bs[k4 * 4 + 1][msl] = v.y;
        Bs[k4 * 4 + 2][msl] = v.z; Bs[k4 * 4 + 3][msl] = v.w;
      }
    }
    __syncthreads();
#pragma unroll
    for (int k = 0; k < 32; k++) {
      const float4 a4 = *(const float4*)&As[k][tm0];
      const float4 b4 = *(const float4*)&Bs[k][tn0];
      const float av[4] = {a4.x, a4.y, a4.z, a4.w};
      const float bv[4] = {b4.x, b4.y, b4.z, b4.w};
#pragma unroll
      for (int i = 0; i < 4; i++)
#pragma unroll
        for (int j = 0; j < 4; j++) acc[i][j] = fmaf(av[i], bv[j], acc[i][j]);
    }
  }

  float bj[4];
#pragma unroll
  for (int j = 0; j < 4; j++) bj[j] = bias[n0 + tn0 + j];
#pragma unroll
  for (int i = 0; i < 4; i++) {
    float4 o4;
    o4.x = acc[i][0] + bj[0]; o4.y = acc[i][1] + bj[1];
    o4.z = acc[i][2] + bj[2]; o4.w = acc[i][3] + bj[3];
    *(float4*)(out + (size_t)(m0 + tm0 + i) * G4 + n0 + tn0) = o4;
  }
}

// ---------------------------------------------------------------------------
// Kernel B: bidirectional LSTM recurrence. 16 WGs: bid 0..7 = forward chunk,
// bid 8..15 = backward chunk. Each WG owns 32 hidden units (128 gate rows),
// w_hh slice register-resident (64 f32/thread, 512 threads). Cross-WG h
// broadcast via global memory + per-WG monotonic flags (agent scope).
// ---------------------------------------------------------------------------
__global__ __launch_bounds__(512) void lstm_rec(
    const float* __restrict__ whh_f, const float* __restrict__ whh_b,
    const float* __restrict__ xg_f, const float* __restrict__ xg_b,
    float* hf, float* hb, unsigned int* flags /* [2][8] stride-16 u32 */) {
  const int bid = blockIdx.x;
  const int dir = bid >> 3;
  const int w   = bid & 7;
  const float* whh = dir ? whh_b : whh_f;
  const float* xg  = dir ? xg_b  : xg_f;
  float* hout      = dir ? hb    : hf;
  unsigned int* flagbase = flags + dir * 8 * 16;

  const int tid  = threadIdx.x;
  const int r    = tid >> 2;     // 0..127 local gate row
  const int kq   = tid & 3;      // k quarter
  const int gate = r >> 5;
  const int u    = r & 31;
  const int grow = gate * 256 + w * 32 + u;   // global gate row

  // register-resident weights: w_hh[grow][kq*64 .. kq*64+63]
  float4 wreg[16];
  {
    const float4* wsrc = (const float4*)(whh + (size_t)grow * HDIM + kq * 64);
#pragma unroll
    for (int i = 0; i < 16; i++) wreg[i] = wsrc[i];
  }

  __shared__ float h_lds[4 * 72];   // chunk kq at offset kq*72 (bank-spread)
  __shared__ float xg_lds[128];
  __shared__ float gv_lds[128];

  float c_state = 0.f;              // valid for tid < 32
  bool dead = false;

  for (int s = 0; s < SLEN; s++) {
    const int t = dir ? (SLEN - 1 - s) : s;

    // prefetch this step's input-projection value (independent of h)
    float xval = 0.f;
    if (tid < 128) {
      const int gr2 = (tid >> 5) * 256 + w * 32 + (tid & 31);
      xval = xg[(size_t)t * G4 + gr2];
    }

    if (s > 0) {
      if (tid < 8 && !dead) {
        int guard = 0;
        while (__hip_atomic_load(flagbase + tid * 16, __ATOMIC_ACQUIRE,
                                 __HIP_MEMORY_SCOPE_AGENT) < (unsigned)s) {
          if (++guard > (1 << 21)) { dead = true; break; }
        }
      }
    }
    __syncthreads();   // B1

    if (tid < 256) {
      float hv = 0.f;
      if (s > 0) {
        const int hidx = dir ? (t + 1) : (t - 1);
        hv = __hip_atomic_load(hout + (size_t)hidx * HDIM + tid,
                               __ATOMIC_RELAXED, __HIP_MEMORY_SCOPE_AGENT);
      }
      h_lds[(tid >> 6) * 72 + (tid & 63)] = hv;
    }
    if (tid < 128) xg_lds[tid] = xval;
    __syncthreads();   // B2

    // 64-wide partial dot from LDS (broadcast reads) against register weights
    float acc = 0.f;
    const float* hp = &h_lds[kq * 72];
#pragma unroll
    for (int i = 0; i < 16; i++) {
      const float4 h4 = *(const float4*)(hp + i * 4);
      acc = fmaf(wreg[i].x, h4.x, acc);
      acc = fmaf(wreg[i].y, h4.y, acc);
      acc = fmaf(wreg[i].z, h4.z, acc);
      acc = fmaf(wreg[i].w, h4.w, acc);
    }
    acc += __shfl_xor(acc, 1);
    acc += __shfl_xor(acc, 2);
    if (kq == 0) gv_lds[r] = acc + xg_lds[r];
    __syncthreads();   // B3

    if (tid < 32) {
      const float iv = gv_lds[tid];
      const float fv = gv_lds[32 + tid];
      const float gv = gv_lds[64 + tid];
      const float ov = gv_lds[96 + tid];
      const float ii = 1.f / (1.f + expf(-iv));
      const float ff = 1.f / (1.f + expf(-fv));
      const float cg = tanhf(gv);
      const float oo = 1.f / (1.f + expf(-ov));
      c_state = ff * c_state + ii * cg;
      const float h = oo * tanhf(c_state);
      __hip_atomic_store(hout + (size_t)t * HDIM + w * 32 + tid, h,
                         __ATOMIC_RELEASE, __HIP_MEMORY_SCOPE_AGENT);
    }
    __syncthreads();   // B4 (drains vmcnt: h stores visible before flag)

    if (tid == 0) {
      __threadfence();
      __hip_atomic_store(flagbase + w * 16, (unsigned)(s + 1),
                         __ATOMIC_RELEASE, __HIP_MEMORY_SCOPE_AGENT);
    }
  }
}

// ---------------------------------------------------------------------------
// Kernel C: feats[t][n] = b_tag[n] + sum_k [hf|hb][t][k] * W_tag[n][k]
// One wave per row t; shuffle reduction.
// ---------------------------------------------------------------------------
__global__ __launch_bounds__(256) void feats_k(
    const float* __restrict__ hf, const float* __restrict__ hb,
    const float* __restrict__ Wtag, const float* __restrict__ btag,
    float* __restrict__ feats) {
  const int gw   = (blockIdx.x * 256 + threadIdx.x) >> 6;  // global wave = t
  const int lane = threadIdx.x & 63;
  float v[8];
#pragma unroll
  for (int j = 0; j < 4; j++) v[j]     = hf[(size_t)gw * HDIM + lane + 64 * j];
#pragma unroll
  for (int j = 0; j < 4; j++) v[4 + j] = hb[(size_t)gw * HDIM + lane + 64 * j];
#pragma unroll
  for (int n = 0; n < NTAG; n++) {
    float acc = 0.f;
#pragma unroll
    for (int j = 0; j < 8; j++)
      acc = fmaf(v[j], Wtag[n * 512 + lane + 64 * j], acc);
#pragma unroll
    for (int off = 32; off; off >>= 1) acc += __shfl_xor(acc, off);
    if (lane == 0) feats[(size_t)gw * 8 + n] = acc + btag[n];
  }
}

// ---------------------------------------------------------------------------
// Kernel D: Viterbi decode, single wave. feats chunked to LDS; backpointers
// packed 4 bits/tag into one u32 per step in LDS; first-max tie-breaking.
// out[0] = score, out[1+t] = path[t] (as f32).
// ---------------------------------------------------------------------------
__global__ __launch_bounds__(64) void viterbi_k(
    const float* __restrict__ feats, const float* __restrict__ trans,
    float* __restrict__ outp) {
  __shared__ float fbuf[512 * 8];        // 16 KB feats chunk
  __shared__ unsigned int bp_lds[SLEN];  // 16 KB packed backpointers

  const int lane = threadIdx.x;
  const int n = (lane < NTAG) ? lane : 0;
  float trow[NTAG];
#pragma unroll
  for (int p = 0; p < NTAG; p++) trow[p] = trans[n * NTAG + p];
  float fv = (lane == START_TAG) ? 0.f : NEGV;

  for (int chunk = 0; chunk < SLEN; chunk += 512) {
    for (int i = 0; i < 64; i++)
      fbuf[i * 64 + lane] = feats[(size_t)chunk * 8 + i * 64 + lane];
    __syncthreads();
    for (int tt = 0; tt < 512; tt++) {
      float best = __shfl(fv, 0) + trow[0];
      int bestp = 0;
#pragma unroll
      for (int p = 1; p < NTAG; p++) {
        const float sc = __shfl(fv, p) + trow[p];
        if (sc > best) { best = sc; bestp = p; }   // strict >: first-max wins
      }
      fv = best + fbuf[tt * 8 + n];
      unsigned int word = 0;
#pragma unroll
      for (int p = 0; p < NTAG; p++)
        word |= (unsigned)(__shfl(bestp, p) & 0xF) << (4 * p);
      if (lane == 0) bp_lds[chunk + tt] = word;
    }
    __syncthreads();
  }

  // terminal = fv + transitions[STOP][:]
  const float term = fv + trans[STOP_TAG * NTAG + n];
  int best = 0;
  float bs = __shfl(term, 0);
#pragma unroll
  for (int p = 1; p < NTAG; p++) {
    const float v = __shfl(term, p);
    if (v > bs) { bs = v; best = p; }
  }
  if (lane == 0) outp[0] = bs;

  __syncthreads();
  int tag = best;
  for (int t = SLEN - 1; t >= 0; t--) {
    if (lane == 0) outp[1 + t] = (float)tag;
    const unsigned int word = bp_lds[t];
    tag = (int)((word >> (4 * tag)) & 0xF);
  }
}

// ---------------------------------------------------------------------------
extern "C" void kernel_launch(void* const* d_in, const int* in_sizes, int n_in,
                              void* d_out, int out_size, void* d_ws, size_t ws_size,
                              hipStream_t stream) {
  const int*   sentence = (const int*)d_in[0];
  const float* embed    = (const float*)d_in[1];
  const float* wih_f    = (const float*)d_in[2];
  const float* whh_f    = (const float*)d_in[3];
  const float* b_f      = (const float*)d_in[4];
  const float* wih_b    = (const float*)d_in[5];
  const float* whh_b    = (const float*)d_in[6];
  const float* b_b      = (const float*)d_in[7];
  const float* Wtag     = (const float*)d_in[8];
  const float* btag     = (const float*)d_in[9];
  const float* trans    = (const float*)d_in[10];
  float* out = (float*)d_out;

  float* xg_f  = (float*)d_ws;
  float* xg_b  = xg_f + (size_t)SLEN * G4;
  float* hf    = xg_b + (size_t)SLEN * G4;
  float* hb    = hf   + (size_t)SLEN * HDIM;
  float* feats = hb   + (size_t)SLEN * HDIM;
  unsigned int* flags = (unsigned int*)(feats + (size_t)SLEN * 8);

  hipMemsetAsync(flags, 0, 2 * 8 * 16 * sizeof(unsigned int), stream);

  dim3 gA(SLEN / 64, G4 / 64, 2);
  xg_gemm<<<gA, 256, 0, stream>>>(embed, sentence, wih_f, b_f, wih_b, b_b, xg_f, xg_b);
  lstm_rec<<<16, 512, 0, stream>>>(whh_f, whh_b, xg_f, xg_b, hf, hb, flags);
  feats_k<<<SLEN * 64 / 256, 256, 0, stream>>>(hf, hb, Wtag, btag, feats);
  viterbi_k<<<1, 64, 0, stream>>>(feats, trans, out);
}

// Round 2
// 10626.706 us; speedup vs baseline: 1.0907x; 1.0907x over previous
//
#include <hip/hip_runtime.h>
#include <math.h>

#define SLEN 4096
#define EDIM 256
#define HDIM 256
#define G4   1024
#define NTAG 5
#define NEGV -10000.0f
#define START_TAG 3
#define STOP_TAG 4
#define SENT 0x7F7F7F7FU   // memset pattern: impossible h value (|h|<1)

// ---------------------------------------------------------------------------
// Kernel A: xg[d][t][r] = b_d[r] + sum_k embed[sentence[t]][k] * w_ih_d[r][k]
// ---------------------------------------------------------------------------
__global__ __launch_bounds__(256) void xg_gemm(
    const float* __restrict__ embed, const int* __restrict__ sent,
    const float* __restrict__ wih_f, const float* __restrict__ b_f,
    const float* __restrict__ wih_b, const float* __restrict__ b_b,
    float* __restrict__ xg_f, float* __restrict__ xg_b) {
  const int dir = blockIdx.z;
  const float* wih  = dir ? wih_b : wih_f;
  const float* bias = dir ? b_b  : b_f;
  float* out        = dir ? xg_b : xg_f;
  const int m0 = blockIdx.x * 64;   // t tile
  const int n0 = blockIdx.y * 64;   // gate-row tile

  __shared__ float As[32][64];      // [k][m]
  __shared__ float Bs[32][64];      // [k][n]
  __shared__ int   srow[64];

  const int tid = threadIdx.x;
  if (tid < 64) srow[tid] = sent[m0 + tid];
  __syncthreads();

  const int tn0 = (tid & 15) * 4;
  const int tm0 = (tid >> 4) * 4;
  float acc[4][4];
#pragma unroll
  for (int i = 0; i < 4; i++)
#pragma unroll
    for (int j = 0; j < 4; j++) acc[i][j] = 0.f;

  const int msl = tid & 63;
  const int k4b = tid >> 6;

  for (int kk = 0; kk < EDIM; kk += 32) {
    __syncthreads();
    {
      const int row = srow[msl];
#pragma unroll
      for (int rep = 0; rep < 2; rep++) {
        const int k4 = k4b + rep * 4;
        const float4 v = *(const float4*)(embed + (size_t)row * EDIM + kk + k4 * 4);
        As[k4 * 4 + 0][msl] = v.x; As[k4 * 4 + 1][msl] = v.y;
        As[k4 * 4 + 2][msl] = v.z; As[k4 * 4 + 3][msl] = v.w;
      }
#pragma unroll
      for (int rep = 0; rep < 2; rep++) {
        const int k4 = k4b + rep * 4;
        const float4 v = *(const float4*)(wih + (size_t)(n0 + msl) * EDIM + kk + k4 * 4);
        Bs[k4 * 4 + 0][msl] = v.x; Bs[k4 * 4 + 1][msl] = v.y;
        Bs[k4 * 4 + 2][msl] = v.z; Bs[k4 * 4 + 3][msl] = v.w;
      }
    }
    __syncthreads();
#pragma unroll
    for (int k = 0; k < 32; k++) {
      const float4 a4 = *(const float4*)&As[k][tm0];
      const float4 b4 = *(const float4*)&Bs[k][tn0];
      const float av[4] = {a4.x, a4.y, a4.z, a4.w};
      const float bv[4] = {b4.x, b4.y, b4.z, b4.w};
#pragma unroll
      for (int i = 0; i < 4; i++)
#pragma unroll
        for (int j = 0; j < 4; j++) acc[i][j] = fmaf(av[i], bv[j], acc[i][j]);
    }
  }

  float bj[4];
#pragma unroll
  for (int j = 0; j < 4; j++) bj[j] = bias[n0 + tn0 + j];
#pragma unroll
  for (int i = 0; i < 4; i++) {
    float4 o4;
    o4.x = acc[i][0] + bj[0]; o4.y = acc[i][1] + bj[1];
    o4.z = acc[i][2] + bj[2]; o4.w = acc[i][3] + bj[3];
    *(float4*)(out + (size_t)(m0 + tm0 + i) * G4 + n0 + tn0) = o4;
  }
}

// ---------------------------------------------------------------------------
// Kernel B: bidirectional LSTM recurrence, sentinel-payload handshake.
// 16 WGs: bid 0..7 forward chunks, 8..15 backward. Each WG owns 32 hidden
// units (128 gate rows); w_hh slice pinned in VGPRs (64 f32/thread).
// Thread layout: tid = u*16 + kq*4 + gate  (u=unit 0..31, kq=k-quarter,
// gate in torch order i,f,g,o). One __syncthreads per step.
// Consumers poll the h words directly (relaxed agent-scope) until they
// differ from the 0x7F7F7F7F memset sentinel — 1 coherent RT per step.
// ---------------------------------------------------------------------------
__global__ __launch_bounds__(512, 2) void lstm_rec(
    const float* __restrict__ whh_f, const float* __restrict__ whh_b,
    const float* __restrict__ xg_f, const float* __restrict__ xg_b,
    float* hf, float* hb) {
  const int bid = blockIdx.x;
  const int dir = bid >> 3;
  const int w   = bid & 7;
  const float* whh = dir ? whh_b : whh_f;
  const float* xg  = dir ? xg_b  : xg_f;
  float* hout      = dir ? hb    : hf;

  const int tid  = threadIdx.x;
  const int u    = tid >> 4;       // local unit 0..31
  const int idx  = tid & 15;
  const int kq   = idx >> 2;       // k quarter 0..3
  const int g    = idx & 3;        // gate (i,f,g,o)
  const int grow = g * 256 + w * 32 + u;
  const int lane = tid & 63;
  const int base = lane & ~15;     // unit-group leader lane

  // pin w_hh[grow][kq*64 .. +63] in VGPRs; asm makes them opaque so the
  // compiler cannot re-materialize the loads inside the loop
  float4 wreg[16];
  {
    const float4* wsrc = (const float4*)(whh + (size_t)grow * HDIM + kq * 64);
#pragma unroll
    for (int i = 0; i < 16; i++) wreg[i] = wsrc[i];
#pragma unroll
    for (int i = 0; i < 16; i++)
      asm volatile("" : "+v"(wreg[i].x), "+v"(wreg[i].y),
                        "+v"(wreg[i].z), "+v"(wreg[i].w));
  }

  __shared__ __align__(16) float hbuf[2][4][72];  // [buf][kq][64 + pad]
  __shared__ int sdead;
  if (tid == 0) sdead = 0;
  __syncthreads();

  float c_state = 0.f;   // meaningful in leader lanes (idx==0) only

  for (int s = 0; s < SLEN; s++) {
    const int t = dir ? (SLEN - 1 - s) : s;

    // prefetch this step's input-projection term (independent of h chain)
    float xval = 0.f;
    if (kq == 0) xval = xg[(size_t)t * G4 + grow];

    // acquire h[t_prev]: poll payload words until non-sentinel
    if (tid < 256) {
      float hv = 0.f;
      if (s > 0) {
        const int tp = dir ? (t + 1) : (t - 1);
        const unsigned* hp = (const unsigned*)(hout + (size_t)tp * HDIM) + tid;
        unsigned v = SENT;
        if (!sdead) {
          int guard = 0;
          do {
            v = __hip_atomic_load(hp, __ATOMIC_RELAXED, __HIP_MEMORY_SCOPE_AGENT);
            if (v != SENT) break;
          } while (++guard < (1 << 16));
        }
        if (v == SENT) { v = 0u; sdead = 1; }  // fail-fast, no hang
        hv = __uint_as_float(v);
      }
      hbuf[s & 1][tid >> 6][tid & 63] = hv;
    }
    __syncthreads();   // the ONLY barrier per step

    // 64-wide partial dot vs register weights (4 accumulators for ILP)
    const float* hp = hbuf[s & 1][kq];
    float a0 = 0.f, a1 = 0.f, a2 = 0.f, a3 = 0.f;
#pragma unroll
    for (int i = 0; i < 16; i++) {
      const float4 h4 = *(const float4*)(hp + i * 4);
      a0 = fmaf(wreg[i].x, h4.x, a0);
      a1 = fmaf(wreg[i].y, h4.y, a1);
      a2 = fmaf(wreg[i].z, h4.z, a2);
      a3 = fmaf(wreg[i].w, h4.w, a3);
    }
    float acc = (a0 + a1) + (a2 + a3);
    acc += __shfl_xor(acc, 4);   // reduce over kq (bits 2..3 of lane)
    acc += __shfl_xor(acc, 8);
    if (kq == 0) acc += xval;    // kq==0 lanes hold finished gate values

    // gather the 4 gate values into the unit leader lane
    const float fraw = __shfl(acc, base + 1);
    const float graw = __shfl(acc, base + 2);
    const float oraw = __shfl(acc, base + 3);

    if (idx == 0) {
      const float ii = 1.f / (1.f + expf(-acc));
      const float ff = 1.f / (1.f + expf(-fraw));
      const float cg = tanhf(graw);
      const float oo = 1.f / (1.f + expf(-oraw));
      c_state = ff * c_state + ii * cg;
      const float h = oo * tanhf(c_state);
      __hip_atomic_store((unsigned*)(hout + (size_t)t * HDIM + w * 32 + u),
                         __float_as_uint(h),
                         __ATOMIC_RELAXED, __HIP_MEMORY_SCOPE_AGENT);
    }
  }
}

// ---------------------------------------------------------------------------
// Kernel C: feats[t][n] = b_tag[n] + sum_k [hf|hb][t][k] * W_tag[n][k]
// ---------------------------------------------------------------------------
__global__ __launch_bounds__(256) void feats_k(
    const float* __restrict__ hf, const float* __restrict__ hb,
    const float* __restrict__ Wtag, const float* __restrict__ btag,
    float* __restrict__ feats) {
  const int gw   = (blockIdx.x * 256 + threadIdx.x) >> 6;  // global wave = t
  const int lane = threadIdx.x & 63;
  float v[8];
#pragma unroll
  for (int j = 0; j < 4; j++) v[j]     = hf[(size_t)gw * HDIM + lane + 64 * j];
#pragma unroll
  for (int j = 0; j < 4; j++) v[4 + j] = hb[(size_t)gw * HDIM + lane + 64 * j];
#pragma unroll
  for (int n = 0; n < NTAG; n++) {
    float acc = 0.f;
#pragma unroll
    for (int j = 0; j < 8; j++)
      acc = fmaf(v[j], Wtag[n * 512 + lane + 64 * j], acc);
#pragma unroll
    for (int off = 32; off; off >>= 1) acc += __shfl_xor(acc, off);
    if (lane == 0) feats[(size_t)gw * 8 + n] = acc + btag[n];
  }
}

// ---------------------------------------------------------------------------
// Kernel D: Viterbi decode, single wave, first-max tie-breaking.
// out[0] = score, out[1+t] = path[t] (as f32).
// ---------------------------------------------------------------------------
__global__ __launch_bounds__(64) void viterbi_k(
    const float* __restrict__ feats, const float* __restrict__ trans,
    float* __restrict__ outp) {
  __shared__ float fbuf[512 * 8];
  __shared__ unsigned int bp_lds[SLEN];

  const int lane = threadIdx.x;
  const int n = (lane < NTAG) ? lane : 0;
  float trow[NTAG];
#pragma unroll
  for (int p = 0; p < NTAG; p++) trow[p] = trans[n * NTAG + p];
  float fv = (lane == START_TAG) ? 0.f : NEGV;

  for (int chunk = 0; chunk < SLEN; chunk += 512) {
    for (int i = 0; i < 64; i++)
      fbuf[i * 64 + lane] = feats[(size_t)chunk * 8 + i * 64 + lane];
    __syncthreads();
    for (int tt = 0; tt < 512; tt++) {
      float best = __shfl(fv, 0) + trow[0];
      int bestp = 0;
#pragma unroll
      for (int p = 1; p < NTAG; p++) {
        const float sc = __shfl(fv, p) + trow[p];
        if (sc > best) { best = sc; bestp = p; }   // strict >: first-max wins
      }
      fv = best + fbuf[tt * 8 + n];
      unsigned int word = 0;
#pragma unroll
      for (int p = 0; p < NTAG; p++)
        word |= (unsigned)(__shfl(bestp, p) & 0xF) << (4 * p);
      if (lane == 0) bp_lds[chunk + tt] = word;
    }
    __syncthreads();
  }

  const float term = fv + trans[STOP_TAG * NTAG + n];
  int best = 0;
  float bs = __shfl(term, 0);
#pragma unroll
  for (int p = 1; p < NTAG; p++) {
    const float v = __shfl(term, p);
    if (v > bs) { bs = v; best = p; }
  }
  if (lane == 0) outp[0] = bs;

  __syncthreads();
  int tag = best;
  for (int t = SLEN - 1; t >= 0; t--) {
    if (lane == 0) outp[1 + t] = (float)tag;
    const unsigned int word = bp_lds[t];
    tag = (int)((word >> (4 * tag)) & 0xF);
  }
}

// ---------------------------------------------------------------------------
extern "C" void kernel_launch(void* const* d_in, const int* in_sizes, int n_in,
                              void* d_out, int out_size, void* d_ws, size_t ws_size,
                              hipStream_t stream) {
  const int*   sentence = (const int*)d_in[0];
  const float* embed    = (const float*)d_in[1];
  const float* wih_f    = (const float*)d_in[2];
  const float* whh_f    = (const float*)d_in[3];
  const float* b_f      = (const float*)d_in[4];
  const float* wih_b    = (const float*)d_in[5];
  const float* whh_b    = (const float*)d_in[6];
  const float* b_b      = (const float*)d_in[7];
  const float* Wtag     = (const float*)d_in[8];
  const float* btag     = (const float*)d_in[9];
  const float* trans    = (const float*)d_in[10];
  float* out = (float*)d_out;

  float* xg_f  = (float*)d_ws;
  float* xg_b  = xg_f + (size_t)SLEN * G4;
  float* hf    = xg_b + (size_t)SLEN * G4;
  float* hb    = hf   + (size_t)SLEN * HDIM;
  float* feats = hb   + (size_t)SLEN * HDIM;

  // sentinel-fill h buffers (hf and hb are contiguous)
  hipMemsetAsync(hf, 0x7F, 2 * (size_t)SLEN * HDIM * sizeof(float), stream);

  dim3 gA(SLEN / 64, G4 / 64, 2);
  xg_gemm<<<gA, 256, 0, stream>>>(embed, sentence, wih_f, b_f, wih_b, b_b, xg_f, xg_b);
  lstm_rec<<<16, 512, 0, stream>>>(whh_f, whh_b, xg_f, xg_b, hf, hb);
  feats_k<<<SLEN * 64 / 256, 256, 0, stream>>>(hf, hb, Wtag, btag, feats);
  viterbi_k<<<1, 64, 0, stream>>>(feats, trans, out);
}